// Round 8
// baseline (47.321 us; speedup 1.0000x reference)
//
#include <hip/hip_runtime.h>
#include <math.h>

// Problem constants (from reference setup_inputs)
constexpr int B  = 2;
constexpr int Lq = 4096;
constexpr int Lk = 4096;
constexpr int H  = 8;
constexpr int C  = 64;
constexpr int K  = 32;
constexpr float INV_SCALE = 0.125f;
constexpr int HC = H * C;                 // 512 elements: row stride in key/value
constexpr int NKV = B * Lk * H * C;       // 4,194,304 elements per array

typedef _Float16 h2 __attribute__((ext_vector_type(2)));
typedef _Float16 half4_t __attribute__((ext_vector_type(4)));

static __device__ __forceinline__ h2 pack_h2(float lo, float hi) {
    return __builtin_bit_cast(h2, __builtin_amdgcn_cvt_pkrtz(lo, hi));
}

#if __has_builtin(__builtin_amdgcn_fdot2)
static __device__ __forceinline__ float fdot2(h2 a, h2 b, float c) {
    return __builtin_amdgcn_fdot2(a, b, c, false);
}
#else
static __device__ __forceinline__ float fdot2(h2 a, h2 b, float c) {
    return c + (float)a.x * (float)b.x + (float)a.y * (float)b.y;
}
#endif

static __device__ __forceinline__ h2 shfl_h2_xor(h2 v, int m) {
    int i = __builtin_bit_cast(int, v);
    i = __shfl_xor(i, m);
    return __builtin_bit_cast(h2, i);
}

// ---------------- prepass: fp32 K,V -> fp16 in d_ws (streamed) ----------------
__global__ __launch_bounds__(256) void convert_kv_f16(
    const float* __restrict__ key,
    const float* __restrict__ value,
    _Float16*    __restrict__ kh,
    _Float16*    __restrict__ vh)
{
    const int n4 = NKV / 4;               // float4 chunks per array
    for (int i = blockIdx.x * blockDim.x + threadIdx.x;
         i < 2 * n4; i += gridDim.x * blockDim.x) {
        if (i < n4) {
            const float4 v = ((const float4*)key)[i];
            half4_t h = { (_Float16)v.x, (_Float16)v.y, (_Float16)v.z, (_Float16)v.w };
            ((half4_t*)kh)[i] = h;
        } else {
            const float4 v = ((const float4*)value)[i - n4];
            half4_t h = { (_Float16)v.x, (_Float16)v.y, (_Float16)v.z, (_Float16)v.w };
            ((half4_t*)vh)[i - n4] = h;
        }
    }
}

// ---------------- main: 8-lane groups, single memory round ----------------
// One wave per query row. 8 groups of 8 lanes:
//   g  = lane>>3 : group g handles keys {4g..4g+3}
//   c8 = lane&7  : channels [8*c8, 8*c8+8)  (16 B of an fp16 row)
// ALL 8 gathers (4 K + 4 V rows, 16 B each) are issued up-front into
// registers -> one L2-latency round instead of two; softmax runs with
// nothing left in flight to wait on. Score: 4x v_dot2_f32_f16 +
// 3-step reduce (masks 1,2,4). Softmax: cross-group masks 8,16,32.
// PV: packed fp16 fma from registers + fp16 tree reduce.
// XCD pinning: group = bid&15 = (b*H+h); fp16 K+V per (b,h) = 1 MB.
__global__ __launch_bounds__(256) void topk_attn_f16(
    const float*    __restrict__ query,
    const _Float16* __restrict__ keyh,
    const _Float16* __restrict__ valh,
    const int*      __restrict__ pos,
    float*          __restrict__ out)
{
    const int bid    = blockIdx.x;        // 0..16383
    const int group  = bid & 15;          // b*H + h
    const int lchunk = bid >> 4;          // 0..1023
    const int wave   = threadIdx.x >> 6;
    const int lane   = threadIdx.x & 63;
    const int g      = lane >> 3;         // 0..7
    const int c8     = lane & 7;          // 0..7

    const int b = group >> 3;
    const int h = group & 7;
    const int l = lchunk * 4 + wave;

    const size_t row  = ((size_t)(b * Lq + l) * H + h);
    const size_t qoff = row * (size_t)C;

    const int p = pos[row * (size_t)K + (lane & 31)];

    const _Float16* kbase = keyh + (size_t)b * Lk * HC + (size_t)h * C;
    const _Float16* vbase = valh + (size_t)b * Lk * HC + (size_t)h * C;

    // gather offsets for this group's 4 keys (shared by K and V)
    int off[4];
    #pragma unroll
    for (int i = 0; i < 4; ++i)
        off[i] = __shfl(p, 4 * g + i) * HC + 8 * c8;

    // ---- SINGLE memory round: all K rows + V rows into registers ----
    uint4 kv[4], vv[4];
    #pragma unroll
    for (int i = 0; i < 4; ++i) kv[i] = *(const uint4*)(kbase + off[i]);
    #pragma unroll
    for (int i = 0; i < 4; ++i) vv[i] = *(const uint4*)(vbase + off[i]);

    // q channels [8c8, 8c8+8), pre-scaled, packed to 4x half2
    const float4 qa = *(const float4*)(query + qoff + 8 * c8);
    const float4 qb = *(const float4*)(query + qoff + 8 * c8 + 4);
    h2 qp[4];
    qp[0] = pack_h2(qa.x * INV_SCALE, qa.y * INV_SCALE);
    qp[1] = pack_h2(qa.z * INV_SCALE, qa.w * INV_SCALE);
    qp[2] = pack_h2(qb.x * INV_SCALE, qb.y * INV_SCALE);
    qp[3] = pack_h2(qb.z * INV_SCALE, qb.w * INV_SCALE);

    // ---- scores: s[i] = score of key 4g+i, replicated within the group ----
    float s[4];
    #pragma unroll
    for (int i = 0; i < 4; ++i) {
        float t = fdot2(qp[0], __builtin_bit_cast(h2, kv[i].x), 0.0f);
        t = fdot2(qp[1], __builtin_bit_cast(h2, kv[i].y), t);
        t = fdot2(qp[2], __builtin_bit_cast(h2, kv[i].z), t);
        t = fdot2(qp[3], __builtin_bit_cast(h2, kv[i].w), t);
        #pragma unroll
        for (int m = 4; m >= 1; m >>= 1) t += __shfl_xor(t, m);
        s[i] = t;
    }

    // ---- softmax over all 32 keys ----
    float mx = fmaxf(fmaxf(s[0], s[1]), fmaxf(s[2], s[3]));
    mx = fmaxf(mx, __shfl_xor(mx, 8));
    mx = fmaxf(mx, __shfl_xor(mx, 16));
    mx = fmaxf(mx, __shfl_xor(mx, 32));

    float se = 0.0f;
    #pragma unroll
    for (int i = 0; i < 4; ++i) { s[i] = __expf(s[i] - mx); se += s[i]; }
    se += __shfl_xor(se, 8);
    se += __shfl_xor(se, 16);
    se += __shfl_xor(se, 32);
    const float inv = 1.0f / se;

    // ---- PV: packed fp16 accumulate from registers ----
    h2 acc[4] = { h2{0,0}, h2{0,0}, h2{0,0}, h2{0,0} };
    #pragma unroll
    for (int i = 0; i < 4; ++i) {
        const float a = s[i] * inv;
        const h2 a2 = pack_h2(a, a);
        acc[0] = a2 * __builtin_bit_cast(h2, vv[i].x) + acc[0];
        acc[1] = a2 * __builtin_bit_cast(h2, vv[i].y) + acc[1];
        acc[2] = a2 * __builtin_bit_cast(h2, vv[i].z) + acc[2];
        acc[3] = a2 * __builtin_bit_cast(h2, vv[i].w) + acc[3];
    }
    // cross-group tree reduce (masks 8,16,32) in packed fp16
    #pragma unroll
    for (int m = 8; m <= 32; m <<= 1) {
        #pragma unroll
        for (int j = 0; j < 4; ++j)
            acc[j] = acc[j] + shfl_h2_xor(acc[j], m);
    }

    if (g == 0) {
        const float4 o0 = make_float4((float)acc[0].x, (float)acc[0].y,
                                      (float)acc[1].x, (float)acc[1].y);
        const float4 o1 = make_float4((float)acc[2].x, (float)acc[2].y,
                                      (float)acc[3].x, (float)acc[3].y);
        *(float4*)(out + qoff + 8 * c8)     = o0;
        *(float4*)(out + qoff + 8 * c8 + 4) = o1;
    }
}

// ---------------- fallback: proven R2 fp32 kernel (if ws too small) ----------
__global__ __launch_bounds__(256) void topk_attn_f32(
    const float* __restrict__ query,
    const float* __restrict__ key,
    const float* __restrict__ value,
    const int*   __restrict__ pos,
    float*       __restrict__ out)
{
    const int bid    = blockIdx.x;
    const int group  = bid & 15;
    const int lchunk = bid >> 4;
    const int wave   = threadIdx.x >> 6;
    const int lane   = threadIdx.x & 63;
    const int g      = lane >> 4;
    const int c4     = lane & 15;

    const int b = group >> 3;
    const int h = group & 7;
    const int l = lchunk * 4 + wave;

    const size_t row  = ((size_t)(b * Lq + l) * H + h);
    const size_t qoff = row * (size_t)C;

    float4 q4 = *(const float4*)(query + qoff + 4 * c4);
    q4.x *= INV_SCALE; q4.y *= INV_SCALE; q4.z *= INV_SCALE; q4.w *= INV_SCALE;

    const int p = pos[row * (size_t)K + (lane & 31)];

    const float* kbase = key   + (size_t)b * Lk * HC + (size_t)h * C;
    const float* vbase = value + (size_t)b * Lk * HC + (size_t)h * C;

    int off[8];
    #pragma unroll
    for (int i = 0; i < 8; ++i)
        off[i] = __shfl(p, 4 * i + g) * HC + 4 * c4;

    float s[8];
    #pragma unroll
    for (int i = 0; i < 8; ++i) {
        const float4 kv = *(const float4*)(kbase + off[i]);
        float t = q4.x * kv.x;
        t = fmaf(q4.y, kv.y, t);
        t = fmaf(q4.z, kv.z, t);
        t = fmaf(q4.w, kv.w, t);
        #pragma unroll
        for (int m = 8; m >= 1; m >>= 1) t += __shfl_xor(t, m);
        s[i] = t;
    }

    float mx = s[0];
    #pragma unroll
    for (int i = 1; i < 8; ++i) mx = fmaxf(mx, s[i]);
    mx = fmaxf(mx, __shfl_xor(mx, 16));
    mx = fmaxf(mx, __shfl_xor(mx, 32));

    float se = 0.0f;
    #pragma unroll
    for (int i = 0; i < 8; ++i) { s[i] = __expf(s[i] - mx); se += s[i]; }
    se += __shfl_xor(se, 16);
    se += __shfl_xor(se, 32);
    const float inv = 1.0f / se;

    float4 acc = make_float4(0.f, 0.f, 0.f, 0.f);
    #pragma unroll
    for (int i = 0; i < 8; ++i) {
        const float a = s[i] * inv;
        const float4 v4 = *(const float4*)(vbase + off[i]);
        acc.x = fmaf(a, v4.x, acc.x);
        acc.y = fmaf(a, v4.y, acc.y);
        acc.z = fmaf(a, v4.z, acc.z);
        acc.w = fmaf(a, v4.w, acc.w);
    }
    #pragma unroll
    for (int m = 16; m <= 32; m <<= 1) {
        acc.x += __shfl_xor(acc.x, m);
        acc.y += __shfl_xor(acc.y, m);
        acc.z += __shfl_xor(acc.z, m);
        acc.w += __shfl_xor(acc.w, m);
    }

    if (g == 0) *(float4*)(out + qoff + 4 * c4) = acc;
}

extern "C" void kernel_launch(void* const* d_in, const int* in_sizes, int n_in,
                              void* d_out, int out_size, void* d_ws, size_t ws_size,
                              hipStream_t stream) {
    const float* query = (const float*)d_in[0];
    const float* key   = (const float*)d_in[1];
    const float* value = (const float*)d_in[2];
    const int*   pos   = (const int*)d_in[3];
    float* out = (float*)d_out;

    const int total_rows = B * Lq * H;          // 65536
    const int blocks = total_rows / 4;          // 16384 (4 waves/block)

    const size_t need = (size_t)2 * NKV * sizeof(_Float16);  // 16.8 MB
    if (ws_size >= need && d_ws != nullptr) {
        _Float16* kh = (_Float16*)d_ws;
        _Float16* vh = kh + NKV;
        convert_kv_f16<<<2048, 256, 0, stream>>>(key, value, kh, vh);
        topk_attn_f16<<<blocks, 256, 0, stream>>>(query, kh, vh, pos, out);
    } else {
        topk_attn_f32<<<blocks, 256, 0, stream>>>(query, key, value, pos, out);
    }
}

// Round 11
// 45.683 us; speedup vs baseline: 1.0359x; 1.0359x over previous
//
#include <hip/hip_runtime.h>
#include <math.h>

// Problem constants (from reference setup_inputs)
constexpr int B  = 2;
constexpr int Lq = 4096;
constexpr int Lk = 4096;
constexpr int H  = 8;
constexpr int C  = 64;
constexpr int K  = 32;
constexpr float INV_SCALE = 0.125f;
constexpr int HC = H * C;                 // 512 elements: row stride in key/value
constexpr int NKV = B * Lk * H * C;       // 4,194,304 elements per array

typedef _Float16 h2 __attribute__((ext_vector_type(2)));
typedef _Float16 half4_t __attribute__((ext_vector_type(4)));

static __device__ __forceinline__ h2 pack_h2(float lo, float hi) {
    return __builtin_bit_cast(h2, __builtin_amdgcn_cvt_pkrtz(lo, hi));
}

#if __has_builtin(__builtin_amdgcn_fdot2)
static __device__ __forceinline__ float fdot2(h2 a, h2 b, float c) {
    return __builtin_amdgcn_fdot2(a, b, c, false);
}
#else
static __device__ __forceinline__ float fdot2(h2 a, h2 b, float c) {
    return c + (float)a.x * (float)b.x + (float)a.y * (float)b.y;
}
#endif

static __device__ __forceinline__ h2 shfl_h2_xor(h2 v, int m) {
    int i = __builtin_bit_cast(int, v);
    i = __shfl_xor(i, m);
    return __builtin_bit_cast(h2, i);
}

// ---- DPP cross-lane (VALU pipe, not DS) ----
// ctrl: 0xB1 = quad_perm[1,0,3,2] (xor1); 0x4E = quad_perm[2,3,0,1] (xor2);
// 0x141 = ROW_HALF_MIRROR (== xor4 AFTER xor1+xor2 reduces, quad-uniform);
// 0x128 = ROW_ROR:8 (== xor8 exactly, 16-lane rows).
template<int CTRL>
static __device__ __forceinline__ float dpp_f(float x) {
    return __builtin_bit_cast(float,
        __builtin_amdgcn_update_dpp(0, __builtin_bit_cast(int, x),
                                    CTRL, 0xF, 0xF, true));
}
template<int CTRL>
static __device__ __forceinline__ h2 dpp_h2(h2 x) {
    return __builtin_bit_cast(h2,
        __builtin_amdgcn_update_dpp(0, __builtin_bit_cast(int, x),
                                    CTRL, 0xF, 0xF, true));
}

// ---------------- prepass: fp32 K,V -> fp16 in d_ws (streamed) ----------------
__global__ __launch_bounds__(256) void convert_kv_f16(
    const float* __restrict__ key,
    const float* __restrict__ value,
    _Float16*    __restrict__ kh,
    _Float16*    __restrict__ vh)
{
    const int n4 = NKV / 4;               // float4 chunks per array
    for (int i = blockIdx.x * blockDim.x + threadIdx.x;
         i < 2 * n4; i += gridDim.x * blockDim.x) {
        if (i < n4) {
            const float4 v = ((const float4*)key)[i];
            half4_t h = { (_Float16)v.x, (_Float16)v.y, (_Float16)v.z, (_Float16)v.w };
            ((half4_t*)kh)[i] = h;
        } else {
            const float4 v = ((const float4*)value)[i - n4];
            half4_t h = { (_Float16)v.x, (_Float16)v.y, (_Float16)v.z, (_Float16)v.w };
            ((half4_t*)vh)[i - n4] = h;
        }
    }
}

// ---------------- main: R8 structure + DPP reduces (DS -> VALU) ----------------
// One wave per query row. 8 groups of 8 lanes:
//   g  = lane>>3 : group g handles keys {4g..4g+3}
//   c8 = lane&7  : channels [8*c8, 8*c8+8)  (16 B of an fp16 row)
// Score reduce (masks 1,2,4): all DPP. Softmax/PV xor8 level: DPP ROW_ROR:8.
// Only xor16/xor32 remain as DS shuffles (12 DS ops vs R8's 34) -> the
// dependent cross-lane chains move from the ~100cy DS pipe to ~2cy VALU.
// pos: direct int4 load per lane (group-uniform) replaces load+4 shfl.
// XCD pinning: group = bid&15 = (b*H+h); fp16 K+V per (b,h) = 1 MB,
// 2 groups/XCD -> 2 MB resident in that XCD's 4 MB L2.
__global__ __launch_bounds__(256) void topk_attn_f16(
    const float*    __restrict__ query,
    const _Float16* __restrict__ keyh,
    const _Float16* __restrict__ valh,
    const int*      __restrict__ pos,
    float*          __restrict__ out)
{
    const int bid    = blockIdx.x;        // 0..16383
    const int group  = bid & 15;          // b*H + h
    const int lchunk = bid >> 4;          // 0..1023
    const int wave   = threadIdx.x >> 6;
    const int lane   = threadIdx.x & 63;
    const int g      = lane >> 3;         // 0..7
    const int c8     = lane & 7;          // 0..7

    const int b = group >> 3;
    const int h = group & 7;
    const int l = lchunk * 4 + wave;

    const size_t row  = ((size_t)(b * Lq + l) * H + h);
    const size_t qoff = row * (size_t)C;

    // this group's 4 pos entries, loaded directly (no broadcast shuffles)
    const int4 pq = *(const int4*)(pos + row * (size_t)K + 4 * g);
    const int pks[4] = { pq.x, pq.y, pq.z, pq.w };

    const _Float16* kbase = keyh + (size_t)b * Lk * HC + (size_t)h * C;
    const _Float16* vbase = valh + (size_t)b * Lk * HC + (size_t)h * C;

    int off[4];
    #pragma unroll
    for (int i = 0; i < 4; ++i)
        off[i] = pks[i] * HC + 8 * c8;

    // ---- all 4 K rows + 4 V rows into registers ----
    uint4 kv[4], vv[4];
    #pragma unroll
    for (int i = 0; i < 4; ++i) kv[i] = *(const uint4*)(kbase + off[i]);
    #pragma unroll
    for (int i = 0; i < 4; ++i) vv[i] = *(const uint4*)(vbase + off[i]);

    // q channels [8c8, 8c8+8), pre-scaled, packed to 4x half2
    const float4 qa = *(const float4*)(query + qoff + 8 * c8);
    const float4 qb = *(const float4*)(query + qoff + 8 * c8 + 4);
    h2 qp[4];
    qp[0] = pack_h2(qa.x * INV_SCALE, qa.y * INV_SCALE);
    qp[1] = pack_h2(qa.z * INV_SCALE, qa.w * INV_SCALE);
    qp[2] = pack_h2(qb.x * INV_SCALE, qb.y * INV_SCALE);
    qp[3] = pack_h2(qb.z * INV_SCALE, qb.w * INV_SCALE);

    // ---- scores: s[i] = score of key 4g+i, replicated within the group ----
    float s[4];
    #pragma unroll
    for (int i = 0; i < 4; ++i) {
        float t = fdot2(qp[0], __builtin_bit_cast(h2, kv[i].x), 0.0f);
        t = fdot2(qp[1], __builtin_bit_cast(h2, kv[i].y), t);
        t = fdot2(qp[2], __builtin_bit_cast(h2, kv[i].z), t);
        t = fdot2(qp[3], __builtin_bit_cast(h2, kv[i].w), t);
        // 8-lane reduce, all VALU DPP
        t += dpp_f<0xB1>(t);     // xor1
        t += dpp_f<0x4E>(t);     // xor2
        t += dpp_f<0x141>(t);    // xor4 (half-mirror, valid after xor1+xor2)
        s[i] = t;
    }

    // ---- softmax over all 32 keys ----
    float mx = fmaxf(fmaxf(s[0], s[1]), fmaxf(s[2], s[3]));
    mx = fmaxf(mx, dpp_f<0x128>(mx));        // xor8 via ROW_ROR:8
    mx = fmaxf(mx, __shfl_xor(mx, 16));
    mx = fmaxf(mx, __shfl_xor(mx, 32));

    float se = 0.0f;
    #pragma unroll
    for (int i = 0; i < 4; ++i) { s[i] = __expf(s[i] - mx); se += s[i]; }
    se += dpp_f<0x128>(se);                  // xor8
    se += __shfl_xor(se, 16);
    se += __shfl_xor(se, 32);
    const float inv = 1.0f / se;

    // ---- PV: packed fp16 accumulate from registers ----
    h2 acc[4] = { h2{0,0}, h2{0,0}, h2{0,0}, h2{0,0} };
    #pragma unroll
    for (int i = 0; i < 4; ++i) {
        const float a = s[i] * inv;
        const h2 a2 = pack_h2(a, a);
        acc[0] = a2 * __builtin_bit_cast(h2, vv[i].x) + acc[0];
        acc[1] = a2 * __builtin_bit_cast(h2, vv[i].y) + acc[1];
        acc[2] = a2 * __builtin_bit_cast(h2, vv[i].z) + acc[2];
        acc[3] = a2 * __builtin_bit_cast(h2, vv[i].w) + acc[3];
    }
    // cross-group tree reduce: xor8 on VALU, xor16/32 via DS
    #pragma unroll
    for (int j = 0; j < 4; ++j) acc[j] = acc[j] + dpp_h2<0x128>(acc[j]);
    #pragma unroll
    for (int j = 0; j < 4; ++j) acc[j] = acc[j] + shfl_h2_xor(acc[j], 16);
    #pragma unroll
    for (int j = 0; j < 4; ++j) acc[j] = acc[j] + shfl_h2_xor(acc[j], 32);

    if (g == 0) {
        const float4 o0 = make_float4((float)acc[0].x, (float)acc[0].y,
                                      (float)acc[1].x, (float)acc[1].y);
        const float4 o1 = make_float4((float)acc[2].x, (float)acc[2].y,
                                      (float)acc[3].x, (float)acc[3].y);
        *(float4*)(out + qoff + 8 * c8)     = o0;
        *(float4*)(out + qoff + 8 * c8 + 4) = o1;
    }
}

// ---------------- fallback: proven R2 fp32 kernel (if ws too small) ----------
__global__ __launch_bounds__(256) void topk_attn_f32(
    const float* __restrict__ query,
    const float* __restrict__ key,
    const float* __restrict__ value,
    const int*   __restrict__ pos,
    float*       __restrict__ out)
{
    const int bid    = blockIdx.x;
    const int group  = bid & 15;
    const int lchunk = bid >> 4;
    const int wave   = threadIdx.x >> 6;
    const int lane   = threadIdx.x & 63;
    const int g      = lane >> 4;
    const int c4     = lane & 15;

    const int b = group >> 3;
    const int h = group & 7;
    const int l = lchunk * 4 + wave;

    const size_t row  = ((size_t)(b * Lq + l) * H + h);
    const size_t qoff = row * (size_t)C;

    float4 q4 = *(const float4*)(query + qoff + 4 * c4);
    q4.x *= INV_SCALE; q4.y *= INV_SCALE; q4.z *= INV_SCALE; q4.w *= INV_SCALE;

    const int p = pos[row * (size_t)K + (lane & 31)];

    const float* kbase = key   + (size_t)b * Lk * HC + (size_t)h * C;
    const float* vbase = value + (size_t)b * Lk * HC + (size_t)h * C;

    int off[8];
    #pragma unroll
    for (int i = 0; i < 8; ++i)
        off[i] = __shfl(p, 4 * i + g) * HC + 4 * c4;

    float s[8];
    #pragma unroll
    for (int i = 0; i < 8; ++i) {
        const float4 kv = *(const float4*)(kbase + off[i]);
        float t = q4.x * kv.x;
        t = fmaf(q4.y, kv.y, t);
        t = fmaf(q4.z, kv.z, t);
        t = fmaf(q4.w, kv.w, t);
        #pragma unroll
        for (int m = 8; m >= 1; m >>= 1) t += __shfl_xor(t, m);
        s[i] = t;
    }

    float mx = s[0];
    #pragma unroll
    for (int i = 1; i < 8; ++i) mx = fmaxf(mx, s[i]);
    mx = fmaxf(mx, __shfl_xor(mx, 16));
    mx = fmaxf(mx, __shfl_xor(mx, 32));

    float se = 0.0f;
    #pragma unroll
    for (int i = 0; i < 8; ++i) { s[i] = __expf(s[i] - mx); se += s[i]; }
    se += __shfl_xor(se, 16);
    se += __shfl_xor(se, 32);
    const float inv = 1.0f / se;

    float4 acc = make_float4(0.f, 0.f, 0.f, 0.f);
    #pragma unroll
    for (int i = 0; i < 8; ++i) {
        const float a = s[i] * inv;
        const float4 v4 = *(const float4*)(vbase + off[i]);
        acc.x = fmaf(a, v4.x, acc.x);
        acc.y = fmaf(a, v4.y, acc.y);
        acc.z = fmaf(a, v4.z, acc.z);
        acc.w = fmaf(a, v4.w, acc.w);
    }
    #pragma unroll
    for (int m = 16; m <= 32; m <<= 1) {
        acc.x += __shfl_xor(acc.x, m);
        acc.y += __shfl_xor(acc.y, m);
        acc.z += __shfl_xor(acc.z, m);
        acc.w += __shfl_xor(acc.w, m);
    }

    if (g == 0) *(float4*)(out + qoff + 4 * c4) = acc;
}

extern "C" void kernel_launch(void* const* d_in, const int* in_sizes, int n_in,
                              void* d_out, int out_size, void* d_ws, size_t ws_size,
                              hipStream_t stream) {
    const float* query = (const float*)d_in[0];
    const float* key   = (const float*)d_in[1];
    const float* value = (const float*)d_in[2];
    const int*   pos   = (const int*)d_in[3];
    float* out = (float*)d_out;

    const int total_rows = B * Lq * H;          // 65536
    const int blocks = total_rows / 4;          // 16384 (4 waves/block)

    const size_t need = (size_t)2 * NKV * sizeof(_Float16);  // 16.8 MB
    if (ws_size >= need && d_ws != nullptr) {
        _Float16* kh = (_Float16*)d_ws;
        _Float16* vh = kh + NKV;
        convert_kv_f16<<<2048, 256, 0, stream>>>(key, value, kh, vh);
        topk_attn_f16<<<blocks, 256, 0, stream>>>(query, kh, vh, pos, out);
    } else {
        topk_attn_f32<<<blocks, 256, 0, stream>>>(query, key, value, pos, out);
    }
}